// Round 6
// baseline (426.758 us; speedup 1.0000x reference)
//
#include <hip/hip_runtime.h>
#include <stdint.h>

typedef short  s16x8 __attribute__((ext_vector_type(8)));
typedef float  f32x4 __attribute__((ext_vector_type(4)));

#define HIDDEN 768
#define SEQ    256
#define BATCH  4
#define NPAIR  32896   /* 256*257/2 */

// ---- fp32 -> bf16 round-to-nearest-even (bit trick, no header types) ----
__device__ inline unsigned short f2bf(float f) {
    unsigned int u = __float_as_uint(f);
    u += 0x7FFFu + ((u >> 16) & 1u);
    return (unsigned short)(u >> 16);
}

// ---- Kernel 1: cast X (1024x768 fp32) -> Xb (bf16), packed 4-wide ----
__global__ void cast_x(const float* __restrict__ X, unsigned short* __restrict__ Xb) {
    int idx = blockIdx.x * 256 + threadIdx.x;         // float4 index, 196608 total
    f32x4 v = ((const f32x4*)X)[idx];
    ushort4 o;
    o.x = f2bf(v[0]); o.y = f2bf(v[1]); o.z = f2bf(v[2]); o.w = f2bf(v[3]);
    ((ushort4*)Xb)[idx] = o;
}

// ---- Kernel 2: transpose+cast W halves: Wt[n][k] = W[k + 768*(half)][n'] bf16 ----
__global__ void transpose_w(const float* __restrict__ W, unsigned short* __restrict__ Wt) {
    __shared__ float tile[32][33];
    const float*     Wh  = W  + (size_t)blockIdx.z * HIDDEN * HIDDEN;
    unsigned short*  Wth = Wt + (size_t)blockIdx.z * HIDDEN * HIDDEN;
    int tx = threadIdx.x, ty = threadIdx.y;
    int k0 = blockIdx.x * 32, n0 = blockIdx.y * 32;
#pragma unroll
    for (int r = 0; r < 4; ++r)
        tile[ty + 8*r][tx] = Wh[(size_t)(k0 + ty + 8*r) * HIDDEN + n0 + tx];
    __syncthreads();
#pragma unroll
    for (int r = 0; r < 4; ++r)
        Wth[(size_t)(n0 + ty + 8*r) * HIDDEN + k0 + tx] = f2bf(tile[tx][ty + 8*r]);
}

// ---- Kernel 3: bf16 MFMA GEMM: C(1024x1536) = Xb @ [W1|W2] -> L(+bias), R fp32 ----
__global__ __launch_bounds__(256) void gemm_lr(const unsigned short* __restrict__ Xb,
                                               const unsigned short* __restrict__ Wt,
                                               const float* __restrict__ bias,
                                               float* __restrict__ L,
                                               float* __restrict__ R) {
    __shared__ unsigned short Als[64][32];   // A tile: [m][k], 4KB
    __shared__ unsigned short Bls[64][32];   // B^T tile: [n][k], 4KB
    const int t    = threadIdx.x;
    const int m0   = blockIdx.y * 64;
    const int nblk = blockIdx.x;
    const bool isL = nblk < 12;
    const int n0   = (isL ? nblk : nblk - 12) * 64;

    const int w = t >> 6, lane = t & 63, quad = lane >> 4, l16 = lane & 15;
    const int wm = (w & 1) * 32, wn = (w >> 1) * 32;

    f32x4 acc00 = {0,0,0,0}, acc01 = {0,0,0,0}, acc10 = {0,0,0,0}, acc11 = {0,0,0,0};

    const int row = t >> 2, seg = t & 3;
    const uint4* Ag = (const uint4*)Xb + (size_t)(m0 + row) * 96 + seg;
    const uint4* Bg = (const uint4*)(Wt + (size_t)nblk * 64 * HIDDEN) + (size_t)row * 96 + seg;
    uint4* Alw = (uint4*)(&Als[0][0]) + t;
    uint4* Blw = (uint4*)(&Bls[0][0]) + t;

    uint4 av = Ag[0], bv = Bg[0];
#pragma unroll 1
    for (int kc = 0; kc < 24; ++kc) {
        *Alw = av; *Blw = bv;
        __syncthreads();
        if (kc < 23) { av = Ag[(kc + 1) * 4]; bv = Bg[(kc + 1) * 4]; }  // prefetch
        s16x8 a0 = *(const s16x8*)&Als[wm      + l16][quad * 8];
        s16x8 a1 = *(const s16x8*)&Als[wm + 16 + l16][quad * 8];
        s16x8 b0 = *(const s16x8*)&Bls[wn      + l16][quad * 8];
        s16x8 b1 = *(const s16x8*)&Bls[wn + 16 + l16][quad * 8];
        acc00 = __builtin_amdgcn_mfma_f32_16x16x32_bf16(a0, b0, acc00, 0, 0, 0);
        acc01 = __builtin_amdgcn_mfma_f32_16x16x32_bf16(a0, b1, acc01, 0, 0, 0);
        acc10 = __builtin_amdgcn_mfma_f32_16x16x32_bf16(a1, b0, acc10, 0, 0, 0);
        acc11 = __builtin_amdgcn_mfma_f32_16x16x32_bf16(a1, b1, acc11, 0, 0, 0);
        __syncthreads();
    }

    float* dst = isL ? L : R;
    const f32x4 accs[2][2] = {{acc00, acc01}, {acc10, acc11}};
#pragma unroll
    for (int mi = 0; mi < 2; ++mi)
#pragma unroll
        for (int ni = 0; ni < 2; ++ni) {
            const int n = n0 + wn + ni * 16 + l16;
            const float badd = isL ? bias[n] : 0.0f;
#pragma unroll
            for (int r = 0; r < 4; ++r) {
                const int m = m0 + wm + mi * 16 + quad * 4 + r;
                dst[(size_t)m * HIDDEN + n] = accs[mi][ni][r] + badd;
            }
        }
}

// ---- Kernel 4: pair expansion. Exact round-0 structure (one block per
//      (pair p, batch b), 192 threads x float4 — the proven-fastest form),
//      with ONE change: plain store instead of nontemporal. Plain stores go
//      through L2 write-combining — the same path the 6.2 TB/s fill kernel
//      uses; nt's no-allocate hint forces direct HBM drains per 1KB
//      wave-store, the suspected 2x write-BW penalty.
__global__ __launch_bounds__(192) void expand(const float* __restrict__ L,
                                              const float* __restrict__ R,
                                              float* __restrict__ out) {
    const int p = blockIdx.x, b = blockIdx.y, t = threadIdx.x;
    // invert row-major triu index: find i with start(i) <= p < start(i+1),
    // start(i) = i*(513-i)/2
    int i = (int)(0.5f * (513.0f - sqrtf(263169.0f - 8.0f * (float)p)));
    if (i < 0) i = 0; if (i > 255) i = 255;
    int s = (i * (513 - i)) >> 1;
    while (s > p) { --i; s = (i * (513 - i)) >> 1; }
    while (p - s >= 256 - i) { s += 256 - i; ++i; }
    const int j = i + (p - s);

    const f32x4 l = ((const f32x4*)(L + (size_t)(b * 256 + i) * HIDDEN))[t];
    const f32x4 r = ((const f32x4*)(R + (size_t)(b * 256 + j) * HIDDEN))[t];
    f32x4 o;
#pragma unroll
    for (int c = 0; c < 4; ++c) {
        const float x = l[c] + r[c];
        const float e = __expf(2.0f * x);                       // v_exp_f32
        o[c] = 1.0f - 2.0f * __builtin_amdgcn_rcpf(e + 1.0f);   // tanh(x), sat-correct
    }
    ((f32x4*)out)[((size_t)b * NPAIR + p) * 192 + t] = o;       // plain store (via L2)
}

extern "C" void kernel_launch(void* const* d_in, const int* in_sizes, int n_in,
                              void* d_out, int out_size, void* d_ws, size_t ws_size,
                              hipStream_t stream) {
    const float* X = (const float*)d_in[0];   // (4,256,768)
    const float* W = (const float*)d_in[1];   // (1536,768)
    const float* b = (const float*)d_in[2];   // (768,)
    float* out = (float*)d_out;               // (4,32896,768) fp32

    char* ws = (char*)d_ws;                   // ~10.2 MB used
    unsigned short* Xb = (unsigned short*)(ws);              // 1024*768*2
    unsigned short* Wt = (unsigned short*)(ws + 1572864);    // 1536*768*2
    float*          L  = (float*)(ws + 3932160);             // 1024*768*4 (bias folded in)
    float*          R  = (float*)(ws + 7077888);             // 1024*768*4

    hipLaunchKernelGGL(cast_x,      dim3(768),          dim3(256),   0, stream, X, Xb);
    hipLaunchKernelGGL(transpose_w, dim3(24, 24, 2),    dim3(32, 8), 0, stream, W, Wt);
    hipLaunchKernelGGL(gemm_lr,     dim3(24, 16),       dim3(256),   0, stream, Xb, Wt, b, L, R);
    hipLaunchKernelGGL(expand,      dim3(NPAIR, BATCH), dim3(192),   0, stream, L, R, out);
}

// Round 7
// 401.322 us; speedup vs baseline: 1.0634x; 1.0634x over previous
//
#include <hip/hip_runtime.h>
#include <stdint.h>

typedef short  s16x8 __attribute__((ext_vector_type(8)));
typedef float  f32x4 __attribute__((ext_vector_type(4)));

#define HIDDEN 768
#define SEQ    256
#define BATCH  4
#define NPAIR  32896   /* 256*257/2 = 8 * 4112, exactly divisible by 8 XCDs */

// ---- fp32 -> bf16 round-to-nearest-even (bit trick, no header types) ----
__device__ inline unsigned short f2bf(float f) {
    unsigned int u = __float_as_uint(f);
    u += 0x7FFFu + ((u >> 16) & 1u);
    return (unsigned short)(u >> 16);
}

// ---- Kernel 1: cast X (1024x768 fp32) -> Xb (bf16), packed 4-wide ----
__global__ void cast_x(const float* __restrict__ X, unsigned short* __restrict__ Xb) {
    int idx = blockIdx.x * 256 + threadIdx.x;         // float4 index, 196608 total
    f32x4 v = ((const f32x4*)X)[idx];
    ushort4 o;
    o.x = f2bf(v[0]); o.y = f2bf(v[1]); o.z = f2bf(v[2]); o.w = f2bf(v[3]);
    ((ushort4*)Xb)[idx] = o;
}

// ---- Kernel 2: transpose+cast W halves: Wt[n][k] = W[k + 768*(half)][n'] bf16 ----
__global__ void transpose_w(const float* __restrict__ W, unsigned short* __restrict__ Wt) {
    __shared__ float tile[32][33];
    const float*     Wh  = W  + (size_t)blockIdx.z * HIDDEN * HIDDEN;
    unsigned short*  Wth = Wt + (size_t)blockIdx.z * HIDDEN * HIDDEN;
    int tx = threadIdx.x, ty = threadIdx.y;
    int k0 = blockIdx.x * 32, n0 = blockIdx.y * 32;
#pragma unroll
    for (int r = 0; r < 4; ++r)
        tile[ty + 8*r][tx] = Wh[(size_t)(k0 + ty + 8*r) * HIDDEN + n0 + tx];
    __syncthreads();
#pragma unroll
    for (int r = 0; r < 4; ++r)
        Wth[(size_t)(n0 + ty + 8*r) * HIDDEN + k0 + tx] = f2bf(tile[tx][ty + 8*r]);
}

// ---- Kernel 3: bf16 MFMA GEMM: C(1024x1536) = Xb @ [W1|W2] -> L(+bias), R fp32 ----
__global__ __launch_bounds__(256) void gemm_lr(const unsigned short* __restrict__ Xb,
                                               const unsigned short* __restrict__ Wt,
                                               const float* __restrict__ bias,
                                               float* __restrict__ L,
                                               float* __restrict__ R) {
    __shared__ unsigned short Als[64][32];   // A tile: [m][k], 4KB
    __shared__ unsigned short Bls[64][32];   // B^T tile: [n][k], 4KB
    const int t    = threadIdx.x;
    const int m0   = blockIdx.y * 64;
    const int nblk = blockIdx.x;
    const bool isL = nblk < 12;
    const int n0   = (isL ? nblk : nblk - 12) * 64;

    const int w = t >> 6, lane = t & 63, quad = lane >> 4, l16 = lane & 15;
    const int wm = (w & 1) * 32, wn = (w >> 1) * 32;

    f32x4 acc00 = {0,0,0,0}, acc01 = {0,0,0,0}, acc10 = {0,0,0,0}, acc11 = {0,0,0,0};

    const int row = t >> 2, seg = t & 3;
    const uint4* Ag = (const uint4*)Xb + (size_t)(m0 + row) * 96 + seg;
    const uint4* Bg = (const uint4*)(Wt + (size_t)nblk * 64 * HIDDEN) + (size_t)row * 96 + seg;
    uint4* Alw = (uint4*)(&Als[0][0]) + t;
    uint4* Blw = (uint4*)(&Bls[0][0]) + t;

    uint4 av = Ag[0], bv = Bg[0];
#pragma unroll 1
    for (int kc = 0; kc < 24; ++kc) {
        *Alw = av; *Blw = bv;
        __syncthreads();
        if (kc < 23) { av = Ag[(kc + 1) * 4]; bv = Bg[(kc + 1) * 4]; }  // prefetch
        s16x8 a0 = *(const s16x8*)&Als[wm      + l16][quad * 8];
        s16x8 a1 = *(const s16x8*)&Als[wm + 16 + l16][quad * 8];
        s16x8 b0 = *(const s16x8*)&Bls[wn      + l16][quad * 8];
        s16x8 b1 = *(const s16x8*)&Bls[wn + 16 + l16][quad * 8];
        acc00 = __builtin_amdgcn_mfma_f32_16x16x32_bf16(a0, b0, acc00, 0, 0, 0);
        acc01 = __builtin_amdgcn_mfma_f32_16x16x32_bf16(a0, b1, acc01, 0, 0, 0);
        acc10 = __builtin_amdgcn_mfma_f32_16x16x32_bf16(a1, b0, acc10, 0, 0, 0);
        acc11 = __builtin_amdgcn_mfma_f32_16x16x32_bf16(a1, b1, acc11, 0, 0, 0);
        __syncthreads();
    }

    float* dst = isL ? L : R;
    const f32x4 accs[2][2] = {{acc00, acc01}, {acc10, acc11}};
#pragma unroll
    for (int mi = 0; mi < 2; ++mi)
#pragma unroll
        for (int ni = 0; ni < 2; ++ni) {
            const int n = n0 + wn + ni * 16 + l16;
            const float badd = isL ? bias[n] : 0.0f;
#pragma unroll
            for (int r = 0; r < 4; ++r) {
                const int m = m0 + wm + mi * 16 + quad * 4 + r;
                dst[(size_t)m * HIDDEN + n] = accs[mi][ni][r] + badd;
            }
        }
}

// ---- Kernel 4: pair expansion. Exact round-0 per-pair structure (one block
//      per (pair, batch), 192 threads x float4, nt stores — the proven-fastest
//      form). ONE change: XCD-aware bijective swizzle of blockIdx.x so each of
//      the 8 XCDs owns a CONTIGUOUS band of 4112 pairs. Default round-robin
//      makes every XCD touch all 6.3 MB of L+R (> 4 MB per-XCD L2 -> thrash,
//      reads spill to L3/fabric and contend with the 404 MB write stream).
//      Banded mapping shrinks each XCD's read working set to ~L2-resident and
//      makes its writes a contiguous sweep.
__global__ __launch_bounds__(192) void expand(const float* __restrict__ L,
                                              const float* __restrict__ R,
                                              float* __restrict__ out) {
    const int bid = blockIdx.x, b = blockIdx.y, t = threadIdx.x;
    const int p = (bid & 7) * (NPAIR / 8) + (bid >> 3);   // bijective: 32896 = 8*4112

    // invert row-major triu index: find i with start(i) <= p < start(i+1)
    int i = (int)(0.5f * (513.0f - sqrtf(263169.0f - 8.0f * (float)p)));
    if (i < 0) i = 0; if (i > 255) i = 255;
    int s = (i * (513 - i)) >> 1;
    while (s > p) { --i; s = (i * (513 - i)) >> 1; }
    while (p - s >= 256 - i) { s += 256 - i; ++i; }
    const int j = i + (p - s);

    const f32x4 l = ((const f32x4*)(L + (size_t)(b * 256 + i) * HIDDEN))[t];
    const f32x4 r = ((const f32x4*)(R + (size_t)(b * 256 + j) * HIDDEN))[t];
    f32x4 o;
#pragma unroll
    for (int c = 0; c < 4; ++c) {
        const float x = l[c] + r[c];
        const float e = __expf(2.0f * x);                       // v_exp_f32
        o[c] = 1.0f - 2.0f * __builtin_amdgcn_rcpf(e + 1.0f);   // tanh(x), sat-correct
    }
    __builtin_nontemporal_store(o, (f32x4*)out + ((size_t)b * NPAIR + p) * 192 + t);
}

extern "C" void kernel_launch(void* const* d_in, const int* in_sizes, int n_in,
                              void* d_out, int out_size, void* d_ws, size_t ws_size,
                              hipStream_t stream) {
    const float* X = (const float*)d_in[0];   // (4,256,768)
    const float* W = (const float*)d_in[1];   // (1536,768)
    const float* b = (const float*)d_in[2];   // (768,)
    float* out = (float*)d_out;               // (4,32896,768) fp32

    char* ws = (char*)d_ws;                   // ~10.2 MB used
    unsigned short* Xb = (unsigned short*)(ws);              // 1024*768*2
    unsigned short* Wt = (unsigned short*)(ws + 1572864);    // 1536*768*2
    float*          L  = (float*)(ws + 3932160);             // 1024*768*4 (bias folded in)
    float*          R  = (float*)(ws + 7077888);             // 1024*768*4

    hipLaunchKernelGGL(cast_x,      dim3(768),          dim3(256),   0, stream, X, Xb);
    hipLaunchKernelGGL(transpose_w, dim3(24, 24, 2),    dim3(32, 8), 0, stream, W, Wt);
    hipLaunchKernelGGL(gemm_lr,     dim3(24, 16),       dim3(256),   0, stream, Xb, Wt, b, L, R);
    hipLaunchKernelGGL(expand,      dim3(NPAIR, BATCH), dim3(192),   0, stream, L, R, out);
}